// Round 4
// baseline (2956.740 us; speedup 1.0000x reference)
//
#include <hip/hip_runtime.h>
#include <hip/hip_bf16.h>

using bf16 = __hip_bfloat16;

// Shapes fixed: B=2, S=2048, D=1024, H=16, hd=64, F=2048.
// Global inputs/outputs fp32. Batches processed sequentially; the d_out
// half-region for batch b (8 MB fp32) doubles as scratch (LN1-out, then
// attn-out, then final out). Workspace: exactly 16 MB = 4 x 4MB bf16 regions.
//
//   r0: q [H,S,64]      -> h2    (after attn)
//   r1: k [H,S,64]      -> sb lo (after attn)
//   r2: v [H,S,64]      -> sb hi
//   r3: x2 (residual stream after attention, bf16 [S,D])

__device__ inline float toF(float x) { return x; }
__device__ inline float toF(bf16 x) { return __bfloat162float(x); }
__device__ inline void  stV(float* p, float v) { *p = v; }
__device__ inline void  stV(bf16* p, float v) { *p = __float2bfloat16(v); }

// ---------------------------------------------------------------------------
// LayerNorm: one block per row, D=1024, block=256 (4 elems/thread).
// ---------------------------------------------------------------------------
template <typename Tx, typename To>
__global__ __launch_bounds__(256) void ln_kernel(
    const Tx* __restrict__ x, const float* __restrict__ g,
    const float* __restrict__ b, To* __restrict__ out)
{
    const int D = 1024;
    int row = blockIdx.x;
    int tid = threadIdx.x;
    const Tx* xr = x + (size_t)row * D;

    float vals[4];
    float sum = 0.f, sumsq = 0.f;
#pragma unroll
    for (int i = 0; i < 4; i++) {
        float v = toF(xr[tid + i * 256]);
        vals[i] = v;
        sum += v;
        sumsq += v * v;
    }
#pragma unroll
    for (int off = 32; off > 0; off >>= 1) {
        sum += __shfl_xor(sum, off);
        sumsq += __shfl_xor(sumsq, off);
    }
    __shared__ float s1[4], s2[4];
    int wave = tid >> 6, lane = tid & 63;
    if (lane == 0) { s1[wave] = sum; s2[wave] = sumsq; }
    __syncthreads();
    sum = s1[0] + s1[1] + s1[2] + s1[3];
    sumsq = s2[0] + s2[1] + s2[2] + s2[3];

    float mu = sum * (1.f / D);
    float var = sumsq * (1.f / D) - mu * mu;
    float rstd = rsqrtf(var + 1e-5f);

    To* orow = out + (size_t)row * D;
#pragma unroll
    for (int i = 0; i < 4; i++) {
        int c = tid + i * 256;
        stV(&orow[c], (vals[i] - mu) * rstd * g[c] + b[c]);
    }
}

// ---------------------------------------------------------------------------
// QKV GEMM + fused RoPE + scatter (single batch).
//   A = h_b [S=2048, K=1024] fp32, W = [16,1024,64] fp32
//   out[h, s, kk] ([16,2048,64] bf16), rotated if do_rope.
// 64x64 tile (head = blockIdx.x), BK=16, 256 thr, 4x4 micro.
// ---------------------------------------------------------------------------
__global__ __launch_bounds__(256) void gemm_qkv_kernel(
    const float* __restrict__ A, const float* __restrict__ W,
    bf16* __restrict__ out, int do_rope)
{
    const int K = 1024, S = 2048;
    __shared__ float As[16][68];
    __shared__ float Bs[16][68];

    int tid = threadIdx.x;
    int h = blockIdx.x;
    int m0 = blockIdx.y * 64;

    int tx = tid & 15, ty = tid >> 4;
    int a_k = tid & 15, a_m = tid >> 4;
    int b_n = tid & 63, b_k = tid >> 6;

    float acc[4][4] = {};

    for (int k0 = 0; k0 < K; k0 += 16) {
#pragma unroll
        for (int i = 0; i < 4; i++) {
            int m = a_m + i * 16;
            As[a_k][m] = A[(size_t)(m0 + m) * K + k0 + a_k];
        }
#pragma unroll
        for (int i = 0; i < 4; i++) {
            int k = b_k + i * 4;
            Bs[k][b_n] = W[((size_t)h * K + k0 + k) * 64 + b_n];
        }
        __syncthreads();
#pragma unroll
        for (int k = 0; k < 16; k++) {
            float a[4], bb[4];
#pragma unroll
            for (int i = 0; i < 4; i++) a[i] = As[k][ty * 4 + i];
#pragma unroll
            for (int j = 0; j < 4; j++) bb[j] = Bs[k][tx * 4 + j];
#pragma unroll
            for (int i = 0; i < 4; i++)
#pragma unroll
                for (int j = 0; j < 4; j++) acc[i][j] += a[i] * bb[j];
        }
        __syncthreads();
    }

#pragma unroll
    for (int i = 0; i < 4; i++) {
        int s = m0 + ty * 4 + i;                       // sequence position
        bf16* orow = out + ((size_t)h * S + s) * 64 + tx * 4;
        if (do_rope) {
#pragma unroll
            for (int pr = 0; pr < 2; pr++) {
                int p = tx * 2 + pr;                   // pair idx 0..31
                float theta = powf(10000.f, -(float)p * (1.f / 16.f));
                float ang = (float)s * theta;
                float c = cosf(ang), sn = sinf(ang);
                float e0 = acc[i][2 * pr], e1 = acc[i][2 * pr + 1];
                orow[2 * pr]     = __float2bfloat16(e0 * c - e1 * sn);
                orow[2 * pr + 1] = __float2bfloat16(e1 * c + e0 * sn);
            }
        } else {
#pragma unroll
            for (int j = 0; j < 4; j++) orow[j] = __float2bfloat16(acc[i][j]);
        }
    }
}

// ---------------------------------------------------------------------------
// General GEMM: C[M,N] = A[M,K] @ B[K,N] (+ res), fp32 accum.
// TA/TB/TC/TR independently bf16 or fp32. 64x64 tile, BK=16, 4x4 micro.
// NOTE: A and C must not alias (A-tiles are re-read by other blocks).
// ---------------------------------------------------------------------------
template <typename TA, typename TB, typename TC, typename TR>
__global__ __launch_bounds__(256) void gemm_kernel(
    const TA* __restrict__ A, const TB* __restrict__ B,
    TC* __restrict__ C, const TR* __restrict__ res,
    int M, int N, int K)
{
    __shared__ float As[16][68];
    __shared__ float Bs[16][68];

    int tid = threadIdx.x;
    int m0 = blockIdx.y * 64;
    int n0 = blockIdx.x * 64;
    int tx = tid & 15, ty = tid >> 4;
    int a_k = tid & 15, a_m = tid >> 4;
    int b_n = tid & 63, b_k = tid >> 6;

    float acc[4][4] = {};

    for (int k0 = 0; k0 < K; k0 += 16) {
#pragma unroll
        for (int i = 0; i < 4; i++) {
            int m = a_m + i * 16;
            As[a_k][m] = toF(A[(size_t)(m0 + m) * K + k0 + a_k]);
        }
#pragma unroll
        for (int i = 0; i < 4; i++) {
            int k = b_k + i * 4;
            Bs[k][b_n] = toF(B[(size_t)(k0 + k) * N + n0 + b_n]);
        }
        __syncthreads();
#pragma unroll
        for (int k = 0; k < 16; k++) {
            float a[4], bb[4];
#pragma unroll
            for (int i = 0; i < 4; i++) a[i] = As[k][ty * 4 + i];
#pragma unroll
            for (int j = 0; j < 4; j++) bb[j] = Bs[k][tx * 4 + j];
#pragma unroll
            for (int i = 0; i < 4; i++)
#pragma unroll
                for (int j = 0; j < 4; j++) acc[i][j] += a[i] * bb[j];
        }
        __syncthreads();
    }

#pragma unroll
    for (int i = 0; i < 4; i++) {
        int m = m0 + ty * 4 + i;
#pragma unroll
        for (int j = 0; j < 4; j++) {
            int n = n0 + tx * 4 + j;
            size_t idx = (size_t)m * N + n;
            float v = acc[i][j];
            if (res) v += toF(res[idx]);
            stV(&C[idx], v);
        }
    }
}

// ---------------------------------------------------------------------------
// Dual GEMM + SwiGLU: C = silu(A@B1) * (A@B2). A bf16, B fp32, C bf16.
// ---------------------------------------------------------------------------
__global__ __launch_bounds__(256) void gemm_swiglu_kernel(
    const bf16* __restrict__ A, const float* __restrict__ B1,
    const float* __restrict__ B2, bf16* __restrict__ C,
    int M, int N, int K)
{
    __shared__ float As[16][68];
    __shared__ float Bs1[16][68];
    __shared__ float Bs2[16][68];

    int tid = threadIdx.x;
    int m0 = blockIdx.y * 64;
    int n0 = blockIdx.x * 64;
    int tx = tid & 15, ty = tid >> 4;
    int a_k = tid & 15, a_m = tid >> 4;
    int b_n = tid & 63, b_k = tid >> 6;

    float acc1[4][4] = {};
    float acc2[4][4] = {};

    for (int k0 = 0; k0 < K; k0 += 16) {
#pragma unroll
        for (int i = 0; i < 4; i++) {
            int m = a_m + i * 16;
            As[a_k][m] = toF(A[(size_t)(m0 + m) * K + k0 + a_k]);
        }
#pragma unroll
        for (int i = 0; i < 4; i++) {
            int k = b_k + i * 4;
            size_t off = (size_t)(k0 + k) * N + n0 + b_n;
            Bs1[k][b_n] = B1[off];
            Bs2[k][b_n] = B2[off];
        }
        __syncthreads();
#pragma unroll
        for (int k = 0; k < 16; k++) {
            float a[4], b1[4], b2[4];
#pragma unroll
            for (int i = 0; i < 4; i++) a[i] = As[k][ty * 4 + i];
#pragma unroll
            for (int j = 0; j < 4; j++) { b1[j] = Bs1[k][tx * 4 + j]; b2[j] = Bs2[k][tx * 4 + j]; }
#pragma unroll
            for (int i = 0; i < 4; i++)
#pragma unroll
                for (int j = 0; j < 4; j++) {
                    acc1[i][j] += a[i] * b1[j];
                    acc2[i][j] += a[i] * b2[j];
                }
        }
        __syncthreads();
    }

#pragma unroll
    for (int i = 0; i < 4; i++) {
        int m = m0 + ty * 4 + i;
#pragma unroll
        for (int j = 0; j < 4; j++) {
            int n = n0 + tx * 4 + j;
            float u = acc1[i][j];
            float sg = 1.f / (1.f + __expf(-u));
            C[(size_t)m * N + n] = __float2bfloat16(u * sg * acc2[i][j]);
        }
    }
}

// ---------------------------------------------------------------------------
// Causal flash attention (single batch), fp32 compute. hd=64.
// q,k,v: [H, S, 64] bf16.  Output o[s, h*64+c] fp32 (concat heads, [S,D]).
// Block = 256 threads per 64-query tile; online softmax; P overlays Ks.
// ---------------------------------------------------------------------------
__global__ __launch_bounds__(256) void attn_kernel(
    const bf16* __restrict__ q, const bf16* __restrict__ k,
    const bf16* __restrict__ v, float* __restrict__ o)
{
    const int hd = 64, S = 2048;
    __shared__ float Qs[64][65];
    __shared__ float Ks[64][65];   // reused to hold P after scores
    __shared__ float Vs[64][65];

    int qt = blockIdx.x;
    int h = blockIdx.y;
    int tid = threadIdx.x;
    int m0 = qt * 64;

    const bf16* qbase = q + (size_t)h * S * hd;
    const bf16* kbase = k + (size_t)h * S * hd;
    const bf16* vbase = v + (size_t)h * S * hd;

    for (int idx = tid; idx < 64 * 64; idx += 256) {
        int r = idx >> 6, c = idx & 63;
        Qs[r][c] = toF(qbase[(size_t)(m0 + r) * hd + c]) * 0.125f;  // 1/sqrt(64)
    }

    int qi = tid >> 2;
    int qd = tid & 3;
    float m_i = -INFINITY, l_i = 0.f;
    float O[16];
#pragma unroll
    for (int j = 0; j < 16; j++) O[j] = 0.f;

    __syncthreads();

    for (int kt = 0; kt <= qt; kt++) {
        for (int idx = tid; idx < 64 * 64; idx += 256) {
            int r = idx >> 6, c = idx & 63;
            Ks[r][c] = toF(kbase[(size_t)(kt * 64 + r) * hd + c]);
            Vs[r][c] = toF(vbase[(size_t)(kt * 64 + r) * hd + c]);
        }
        __syncthreads();

        float sc[16];
#pragma unroll
        for (int j = 0; j < 16; j++) sc[j] = 0.f;
#pragma unroll 4
        for (int kk = 0; kk < 64; kk++) {
            float qv = Qs[qi][kk];
#pragma unroll
            for (int j = 0; j < 16; j++) sc[j] += qv * Ks[qd * 16 + j][kk];
        }
        if (kt == qt) {
#pragma unroll
            for (int j = 0; j < 16; j++)
                if (qd * 16 + j > qi) sc[j] = -INFINITY;
        }

        float mx = sc[0];
#pragma unroll
        for (int j = 1; j < 16; j++) mx = fmaxf(mx, sc[j]);
        mx = fmaxf(mx, __shfl_xor(mx, 1));   // combine the 4 row-threads
        mx = fmaxf(mx, __shfl_xor(mx, 2));

        float m_new = fmaxf(m_i, mx);
        float alpha = __expf(m_i - m_new);   // 0 on first tile
        float rowsum = 0.f;
#pragma unroll
        for (int j = 0; j < 16; j++) {
            sc[j] = __expf(sc[j] - m_new);   // masked -> 0
            rowsum += sc[j];
        }
        rowsum += __shfl_xor(rowsum, 1);
        rowsum += __shfl_xor(rowsum, 2);
        l_i = l_i * alpha + rowsum;
        m_i = m_new;
#pragma unroll
        for (int j = 0; j < 16; j++) O[j] *= alpha;

        __syncthreads();                     // done reading Ks as scores
#pragma unroll
        for (int j = 0; j < 16; j++) Ks[qi][qd * 16 + j] = sc[j];
        __syncthreads();                     // P visible

#pragma unroll 4
        for (int s2 = 0; s2 < 64; s2++) {
            float pv = Ks[qi][s2];
#pragma unroll
            for (int j = 0; j < 16; j++) O[j] += pv * Vs[s2][qd * 16 + j];
        }
        __syncthreads();                     // before next tile overwrite
    }

    float inv = 1.f / l_i;
    float* orow = o + (size_t)(m0 + qi) * 1024 + h * hd + qd * 16;
#pragma unroll
    for (int j = 0; j < 16; j++) orow[j] = O[j] * inv;
}

// ---------------------------------------------------------------------------
extern "C" void kernel_launch(void* const* d_in, const int* in_sizes, int n_in,
                              void* d_out, int out_size, void* d_ws, size_t ws_size,
                              hipStream_t stream)
{
    const int S = 2048, D = 1024, F = 2048;

    const float* x    = (const float*)d_in[0];
    const float* ln1g = (const float*)d_in[1];
    const float* ln1b = (const float*)d_in[2];
    const float* Wq   = (const float*)d_in[3];
    const float* Wk   = (const float*)d_in[4];
    const float* Wv   = (const float*)d_in[5];
    const float* Wo   = (const float*)d_in[6];
    const float* ln2g = (const float*)d_in[7];
    const float* ln2b = (const float*)d_in[8];
    const float* W1   = (const float*)d_in[9];
    const float* W2   = (const float*)d_in[10];
    const float* W3   = (const float*)d_in[11];
    float* out = (float*)d_out;

    // workspace: exactly 16 MB = 4 regions x 4 MB bf16 ([S,D] each)
    const size_t NR = (size_t)S * D;        // 2M elements
    bf16* r0 = (bf16*)d_ws;
    bf16* r1 = r0 + NR;
    bf16* r2 = r1 + NR;
    bf16* r3 = r2 + NR;

    for (int b = 0; b < 2; b++) {
        const float* xb = x + (size_t)b * S * D;
        float* ob = out + (size_t)b * S * D;   // d_out half-region as scratch

        // 1. h_b = LN1(x_b) -> ob (fp32)
        ln_kernel<float, float><<<S, 256, 0, stream>>>(xb, ln1g, ln1b, ob);

        // 2-4. q,k,v = h_b @ Wq/Wk/Wv (+RoPE on q,k) -> [H,S,64] bf16
        gemm_qkv_kernel<<<dim3(16, S / 64), 256, 0, stream>>>(ob, Wq, r0, 1);
        gemm_qkv_kernel<<<dim3(16, S / 64), 256, 0, stream>>>(ob, Wk, r1, 1);
        gemm_qkv_kernel<<<dim3(16, S / 64), 256, 0, stream>>>(ob, Wv, r2, 0);

        // 5. attn -> ob (fp32, overwrites dead h_b)
        attn_kernel<<<dim3(S / 64, 16), 256, 0, stream>>>(r0, r1, r2, ob);

        // 6. x2_b = x_b + ob @ Wo -> r3 (bf16)
        gemm_kernel<float, float, bf16, float><<<dim3(D / 64, S / 64), 256, 0, stream>>>(
            ob, Wo, r3, xb, S, D, D);

        // 7. h2_b = LN2(r3) -> r0 (bf16, q dead)
        ln_kernel<bf16, bf16><<<S, 256, 0, stream>>>(r3, ln2g, ln2b, r0);

        // 8. sb = silu(r0@W1) * (r0@W2) -> r1..r2 (8 MB bf16, k/v dead)
        gemm_swiglu_kernel<<<dim3(F / 64, S / 64), 256, 0, stream>>>(r0, W1, W2, r1, S, F, D);

        // 9. out_b = r3 + sb @ W3 -> ob (fp32, attn-out dead)
        gemm_kernel<bf16, float, float, bf16><<<dim3(D / 64, S / 64), 256, 0, stream>>>(
            r1, W3, ob, r3, S, D, F);
    }
}

// Round 5
// 1002.341 us; speedup vs baseline: 2.9498x; 2.9498x over previous
//
#include <hip/hip_runtime.h>
#include <hip/hip_bf16.h>

using bf16 = __hip_bfloat16;
typedef __attribute__((ext_vector_type(8))) short bf16x8;
typedef __attribute__((ext_vector_type(4))) float f32x4;

// Shapes fixed: B=2, S=2048, D=1024, H=16, hd=64, F=2048.
// Global I/O fp32. Batches sequential. ws = 16 MB = 4 bf16 regions r0..r3
// (2M elems each). d_out half (8 MB) doubles as scratch (obB as bf16).
//
// Per-batch region lifetimes (stream-ordered, audited):
//  1  LN1(xb)            -> r3
//  2  WqT/WkT/WvT        -> obB[0:1M)/[1M:2M)/[2M:3M)
//  3  QKV mfma (z=0,1,2) -> r0,r1,r2   (A=r3, B=obB+z*1M, rope z<2)
//  4  attn(r0,r1,r2)     -> obB[0:2M)  (over dead WqT/WkT)
//  5  WoT -> obB[3M:4M); mfma mode2: A=obB[0:2M), B=WoT, res=xb -> x2=r3
//  6  LN2(r3)            -> r0 (h2)
//  7  W1T -> obB[0:2M), W2T -> obB[2M:4M)  (attn-out/WoT dead)
//  8  mfma mode0: A=r0, B=W1T -> u = r1 (spans r1..r2, [2048][2048])
//  9  mfma mode3: A=r0, B=W2T, C=r1 in-place -> sb = silu(u)*g
// 10  W3T -> r0 (h2 dead)
// 11  mfma mode4: A=r1, B=r0(W3T), res=r3(x2) -> ob fp32 (final)

__device__ inline float toF(float x) { return x; }
__device__ inline float toF(bf16 x) { return __bfloat162float(x); }
__device__ inline void  stV(float* p, float v) { *p = v; }
__device__ inline void  stV(bf16* p, float v) { *p = __float2bfloat16(v); }

__device__ __forceinline__ void unpack8(uint4 u, float* f) {
    f[0] = __uint_as_float(u.x << 16); f[1] = __uint_as_float(u.x & 0xffff0000u);
    f[2] = __uint_as_float(u.y << 16); f[3] = __uint_as_float(u.y & 0xffff0000u);
    f[4] = __uint_as_float(u.z << 16); f[5] = __uint_as_float(u.z & 0xffff0000u);
    f[6] = __uint_as_float(u.w << 16); f[7] = __uint_as_float(u.w & 0xffff0000u);
}

__device__ __forceinline__ void gl_lds16(const void* g, void* l) {
    __builtin_amdgcn_global_load_lds(
        (__attribute__((address_space(1))) void*)g,
        (__attribute__((address_space(3))) void*)l, 16, 0, 0);
}

// ---------------------------------------------------------------------------
// LayerNorm: one block per row, D=1024, 256 threads.
// ---------------------------------------------------------------------------
template <typename Tx, typename To>
__global__ __launch_bounds__(256) void ln_kernel(
    const Tx* __restrict__ x, const float* __restrict__ g,
    const float* __restrict__ b, To* __restrict__ out)
{
    const int D = 1024;
    int row = blockIdx.x;
    int tid = threadIdx.x;
    const Tx* xr = x + (size_t)row * D;

    float vals[4];
    float sum = 0.f, sumsq = 0.f;
#pragma unroll
    for (int i = 0; i < 4; i++) {
        float v = toF(xr[tid + i * 256]);
        vals[i] = v; sum += v; sumsq += v * v;
    }
#pragma unroll
    for (int off = 32; off > 0; off >>= 1) {
        sum += __shfl_xor(sum, off);
        sumsq += __shfl_xor(sumsq, off);
    }
    __shared__ float s1[4], s2[4];
    int wave = tid >> 6, lane = tid & 63;
    if (lane == 0) { s1[wave] = sum; s2[wave] = sumsq; }
    __syncthreads();
    sum = s1[0] + s1[1] + s1[2] + s1[3];
    sumsq = s2[0] + s2[1] + s2[2] + s2[3];

    float mu = sum * (1.f / D);
    float var = sumsq * (1.f / D) - mu * mu;
    float rstd = rsqrtf(var + 1e-5f);

    To* orow = out + (size_t)row * D;
#pragma unroll
    for (int i = 0; i < 4; i++) {
        int c = tid + i * 256;
        stV(&orow[c], (vals[i] - mu) * rstd * g[c] + b[c]);
    }
}

// ---------------------------------------------------------------------------
// Transpose+convert: in fp32 [R][C] (per z-slice) -> out bf16 [C][R].
// 32x32 LDS tiles, 256 threads.
// ---------------------------------------------------------------------------
__global__ __launch_bounds__(256) void tconv_kernel(
    const float* __restrict__ in, bf16* __restrict__ out, int R, int C)
{
    __shared__ float t[32][33];
    int hh = blockIdx.z;
    const float* ip = in + (size_t)hh * R * C;
    bf16* op = out + (size_t)hh * R * C;
    int c0 = blockIdx.x * 32, r0 = blockIdx.y * 32;
    int tx = threadIdx.x & 31, ty = threadIdx.x >> 5;  // ty 0..7
#pragma unroll
    for (int i = 0; i < 4; i++)
        t[ty + 8 * i][tx] = ip[(size_t)(r0 + ty + 8 * i) * C + c0 + tx];
    __syncthreads();
#pragma unroll
    for (int i = 0; i < 4; i++)
        op[(size_t)(c0 + ty + 8 * i) * R + r0 + tx] = __float2bfloat16(t[tx][ty + 8 * i]);
}

// ---------------------------------------------------------------------------
// MFMA GEMM: C[M,N] = A[M,K](bf16) @ B (BT[N,K] bf16), fp32 accum.
// 128x128 tile, BK=32, 4 waves (2x2), 4x4 16x16 MFMA subtiles per wave.
// global_load_lds width=16 staging (m97 structure).
// MODE 0: C bf16 = acc
// MODE 1: QKV scatter [H][S][64] + RoPE (z selects B/C; rope for z<2)
// MODE 2: C bf16 = acc + resF32
// MODE 3: C bf16 = silu(C) * acc   (in-place, same idx)
// MODE 4: C f32  = acc + resBf16
// ---------------------------------------------------------------------------
template <int MODE>
__global__ __launch_bounds__(256) void mfma_gemm(
    const bf16* __restrict__ A, const bf16* __restrict__ BT0,
    void* __restrict__ Cv, const void* __restrict__ resv,
    int M, int N, int K)
{
    __shared__ bf16 As[128 * 32];
    __shared__ bf16 Bs[128 * 32];
    int tid = threadIdx.x, lane = tid & 63, w = tid >> 6;
    int wm = w >> 1, wn = w & 1;
    int m0 = blockIdx.y * 128, n0 = blockIdx.x * 128;

    const bf16* BT = BT0;
    bf16* Cq = nullptr; int rope = 0;
    if (MODE == 1) {
        int z = blockIdx.z;
        BT = BT0 + ((size_t)z << 20);          // 1M elems per weight
        Cq = (bf16*)Cv + ((size_t)z << 21);    // 2M elems per output
        rope = (z < 2);
    }

    int srow = lane >> 2, scol = (lane & 3) * 8;
    const bf16* Ag = A + (size_t)(m0 + w * 32 + srow) * K + scol;
    const bf16* Bg = BT + (size_t)(n0 + w * 32 + srow) * K + scol;
    unsigned offAB = (unsigned)__builtin_amdgcn_readfirstlane(w * 2048);
    char* As_c = (char*)As;
    char* Bs_c = (char*)Bs;

    f32x4 acc[4][4];
#pragma unroll
    for (int i = 0; i < 4; i++)
#pragma unroll
        for (int j = 0; j < 4; j++) acc[i][j] = (f32x4){0.f, 0.f, 0.f, 0.f};

    for (int k0 = 0; k0 < K; k0 += 32) {
        gl_lds16(Ag + k0,                 As_c + offAB);
        gl_lds16(Ag + k0 + (size_t)16 * K, As_c + offAB + 1024);
        gl_lds16(Bg + k0,                 Bs_c + offAB);
        gl_lds16(Bg + k0 + (size_t)16 * K, Bs_c + offAB + 1024);
        __syncthreads();

        bf16x8 af[4], bfr[4];
#pragma unroll
        for (int i = 0; i < 4; i++)
            af[i] = *(const bf16x8*)&As[(wm * 64 + i * 16 + (lane & 15)) * 32 + (lane >> 4) * 8];
#pragma unroll
        for (int j = 0; j < 4; j++)
            bfr[j] = *(const bf16x8*)&Bs[(wn * 64 + j * 16 + (lane & 15)) * 32 + (lane >> 4) * 8];
#pragma unroll
        for (int i = 0; i < 4; i++)
#pragma unroll
            for (int j = 0; j < 4; j++)
                acc[i][j] = __builtin_amdgcn_mfma_f32_16x16x32_bf16(af[i], bfr[j], acc[i][j], 0, 0, 0);
        __syncthreads();
    }

    int rbase = (lane >> 4) * 4;
    int cidx = lane & 15;
#pragma unroll
    for (int i = 0; i < 4; i++) {
#pragma unroll
        for (int j = 0; j < 4; j++) {
#pragma unroll
            for (int r = 0; r < 4; r++) {
                int row = m0 + wm * 64 + i * 16 + rbase + r;
                int col = n0 + wn * 64 + j * 16 + cidx;
                float v = acc[i][j][r];
                size_t idx = (size_t)row * N + col;
                if (MODE == 0) {
                    ((bf16*)Cv)[idx] = __float2bfloat16(v);
                } else if (MODE == 1) {
                    int h = col >> 6, kk = col & 63;
                    float outv = v;
                    if (rope) {
                        float other = __shfl_xor(v, 1);   // partner col (kk^1)
                        float p = (float)(kk >> 1);
                        float theta = __expf(p * -0.5756462732485114f); // ln(1e4)/16
                        float ang = (float)row * theta;
                        float c, sn; __sincosf(ang, &sn, &c);
                        outv = (kk & 1) ? (v * c + other * sn) : (v * c - other * sn);
                    }
                    Cq[((size_t)h * 2048 + row) * 64 + kk] = __float2bfloat16(outv);
                } else if (MODE == 2) {
                    v += ((const float*)resv)[idx];
                    ((bf16*)Cv)[idx] = __float2bfloat16(v);
                } else if (MODE == 3) {
                    float u = __bfloat162float(((bf16*)Cv)[idx]);
                    float sg = 1.f / (1.f + __expf(-u));
                    ((bf16*)Cv)[idx] = __float2bfloat16(u * sg * v);
                } else {
                    v += __bfloat162float(((const bf16*)resv)[idx]);
                    ((float*)Cv)[idx] = v;
                }
            }
        }
    }
}

// ---------------------------------------------------------------------------
// Causal flash attention (single batch), VALU fp32, bf16 I/O. hd=64.
// LDS: Q^T[d][qi], K^T[d][s2] (reused as P^T[s2][qi]), V[s2][d].
// Thread = 4x4 register tile; score/PV loops = 2x ds_read_b128 per 16 FMA.
// qt reversed (longest blocks first). Output bf16 [s][h*64+d].
// ---------------------------------------------------------------------------
__global__ __launch_bounds__(256) void attn_kernel(
    const bf16* __restrict__ q, const bf16* __restrict__ k,
    const bf16* __restrict__ v, bf16* __restrict__ o)
{
    const int S = 2048;
    __shared__ float Qt[64][68];
    __shared__ float Kt[64][68];   // scores phase: K^T; PV phase: P^T
    __shared__ float Vs[64][68];

    int qt = 31 - (int)blockIdx.x;
    int h = blockIdx.y;
    int tid = threadIdx.x;
    int m0 = qt * 64;

    const bf16* qb = q + ((size_t)h * S + m0) * 64;
    const bf16* kb = k + (size_t)h * S * 64;
    const bf16* vb = v + (size_t)h * S * 64;

    int sl = tid >> 2;            // staging row 0..63
    int d0 = (tid & 3) * 16;      // staging col group

    {   // stage Q^T (scaled)
        const uint4* src = (const uint4*)(qb + (size_t)sl * 64 + d0);
        uint4 u0 = src[0], u1 = src[1];
        float f[16]; unpack8(u0, f); unpack8(u1, f + 8);
#pragma unroll
        for (int j = 0; j < 16; j++) Qt[d0 + j][sl] = f[j] * 0.125f;
    }

    int c0 = (tid & 15) * 4;      // compute cols
    int r0l = (tid >> 4) * 4;     // compute rows
    float m_i[4], l_i[4], O[4][4];
#pragma unroll
    for (int i = 0; i < 4; i++) {
        m_i[i] = -INFINITY; l_i[i] = 0.f;
#pragma unroll
        for (int j = 0; j < 4; j++) O[i][j] = 0.f;
    }
    __syncthreads();

    for (int kt = 0; kt <= qt; kt++) {
        // global loads first (latency overlap), then barrier, then LDS write
        const uint4* ks = (const uint4*)(kb + ((size_t)(kt * 64 + sl)) * 64 + d0);
        uint4 ka0 = ks[0], ka1 = ks[1];
        const uint4* vsrc = (const uint4*)(vb + ((size_t)(kt * 64 + sl)) * 64 + d0);
        uint4 va0 = vsrc[0], va1 = vsrc[1];
        float kf[16], vf[16];
        unpack8(ka0, kf); unpack8(ka1, kf + 8);
        unpack8(va0, vf); unpack8(va1, vf + 8);

        __syncthreads();   // prev iteration's PV reads done
#pragma unroll
        for (int j = 0; j < 16; j++) Kt[d0 + j][sl] = kf[j];
#pragma unroll
        for (int t = 0; t < 4; t++) {
            float4 v4 = make_float4(vf[4 * t], vf[4 * t + 1], vf[4 * t + 2], vf[4 * t + 3]);
            *(float4*)&Vs[sl][d0 + 4 * t] = v4;
        }
        __syncthreads();

        // scores: sc[i][j] = sum_d Q[r][d] * K[c][d]
        float sc[4][4];
#pragma unroll
        for (int i = 0; i < 4; i++)
#pragma unroll
            for (int j = 0; j < 4; j++) sc[i][j] = 0.f;
#pragma unroll 4
        for (int kk = 0; kk < 64; kk++) {
            float4 qv = *(const float4*)&Qt[kk][r0l];
            float4 kv = *(const float4*)&Kt[kk][c0];
            float qa[4] = {qv.x, qv.y, qv.z, qv.w};
            float kca[4] = {kv.x, kv.y, kv.z, kv.w};
#pragma unroll
            for (int i = 0; i < 4; i++)
#pragma unroll
                for (int j = 0; j < 4; j++) sc[i][j] += qa[i] * kca[j];
        }
        if (kt == qt) {
#pragma unroll
            for (int i = 0; i < 4; i++)
#pragma unroll
                for (int j = 0; j < 4; j++)
                    if (c0 + j > r0l + i) sc[i][j] = -INFINITY;
        }

        // online softmax per row
#pragma unroll
        for (int i = 0; i < 4; i++) {
            float mx = fmaxf(fmaxf(sc[i][0], sc[i][1]), fmaxf(sc[i][2], sc[i][3]));
            mx = fmaxf(mx, __shfl_xor(mx, 1));
            mx = fmaxf(mx, __shfl_xor(mx, 2));
            mx = fmaxf(mx, __shfl_xor(mx, 4));
            mx = fmaxf(mx, __shfl_xor(mx, 8));
            float mnew = fmaxf(m_i[i], mx);
            float alpha = __expf(m_i[i] - mnew);
            float rs = 0.f;
#pragma unroll
            for (int j = 0; j < 4; j++) { sc[i][j] = __expf(sc[i][j] - mnew); rs += sc[i][j]; }
            rs += __shfl_xor(rs, 1);
            rs += __shfl_xor(rs, 2);
            rs += __shfl_xor(rs, 4);
            rs += __shfl_xor(rs, 8);
            l_i[i] = l_i[i] * alpha + rs;
            m_i[i] = mnew;
#pragma unroll
            for (int j = 0; j < 4; j++) O[i][j] *= alpha;
        }

        __syncthreads();   // all done reading Kt as K^T
#pragma unroll
        for (int i = 0; i < 4; i++)
#pragma unroll
            for (int j = 0; j < 4; j++) Kt[c0 + j][r0l + i] = sc[i][j];  // P^T
        __syncthreads();

        // PV: O[i][j] += sum_s P[r][s] * V[s][c]
#pragma unroll 4
        for (int s2 = 0; s2 < 64; s2++) {
            float4 pv = *(const float4*)&Kt[s2][r0l];
            float4 vv = *(const float4*)&Vs[s2][c0];
            float pa[4] = {pv.x, pv.y, pv.z, pv.w};
            float va[4] = {vv.x, vv.y, vv.z, vv.w};
#pragma unroll
            for (int i = 0; i < 4; i++)
#pragma unroll
                for (int j = 0; j < 4; j++) O[i][j] += pa[i] * va[j];
        }
    }

#pragma unroll
    for (int i = 0; i < 4; i++) {
        float inv = 1.f / l_i[i];
#pragma unroll
        for (int j = 0; j < 4; j++)
            o[(size_t)(m0 + r0l + i) * 1024 + h * 64 + c0 + j] = __float2bfloat16(O[i][j] * inv);
    }
}

// ---------------------------------------------------------------------------
extern "C" void kernel_launch(void* const* d_in, const int* in_sizes, int n_in,
                              void* d_out, int out_size, void* d_ws, size_t ws_size,
                              hipStream_t stream)
{
    const int S = 2048, D = 1024;

    const float* x    = (const float*)d_in[0];
    const float* ln1g = (const float*)d_in[1];
    const float* ln1b = (const float*)d_in[2];
    const float* Wq   = (const float*)d_in[3];
    const float* Wk   = (const float*)d_in[4];
    const float* Wv   = (const float*)d_in[5];
    const float* Wo   = (const float*)d_in[6];
    const float* ln2g = (const float*)d_in[7];
    const float* ln2b = (const float*)d_in[8];
    const float* W1   = (const float*)d_in[9];
    const float* W2   = (const float*)d_in[10];
    const float* W3   = (const float*)d_in[11];
    float* out = (float*)d_out;

    const size_t NR = (size_t)S * D;   // 2M elems per 4MB region
    bf16* r0 = (bf16*)d_ws;
    bf16* r1 = r0 + NR;
    bf16* r2 = r1 + NR;
    bf16* r3 = r2 + NR;
    const size_t M1 = 1u << 20;        // 1M elems

    for (int b = 0; b < 2; b++) {
        const float* xb = x + (size_t)b * S * D;
        float* ob = out + (size_t)b * S * D;   // 8 MB scratch / final out
        bf16* obB = (bf16*)ob;                 // up to 4M bf16 elems

        // 1. h = LN1(xb) -> r3 (bf16)
        ln_kernel<float, bf16><<<S, 256, 0, stream>>>(xb, ln1g, ln1b, r3);

        // 2. WqT/WkT/WvT -> obB[0:3M)
        tconv_kernel<<<dim3(2, 32, 16), 256, 0, stream>>>(Wq, obB,          1024, 64);
        tconv_kernel<<<dim3(2, 32, 16), 256, 0, stream>>>(Wk, obB + 1 * M1, 1024, 64);
        tconv_kernel<<<dim3(2, 32, 16), 256, 0, stream>>>(Wv, obB + 2 * M1, 1024, 64);

        // 3. q,k,v (+RoPE) -> r0,r1,r2
        mfma_gemm<1><<<dim3(8, 16, 3), 256, 0, stream>>>(r3, obB, r0, nullptr, S, 1024, 1024);

        // 4. attn -> obB[0:2M) (bf16 [S][D])
        attn_kernel<<<dim3(32, 16), 256, 0, stream>>>(r0, r1, r2, obB);

        // 5. WoT -> obB[3M:4M); x2 = xb + attn@Wo -> r3 (bf16)
        tconv_kernel<<<dim3(32, 32, 1), 256, 0, stream>>>(Wo, obB + 3 * M1, 1024, 1024);
        mfma_gemm<2><<<dim3(8, 16, 1), 256, 0, stream>>>(obB, obB + 3 * M1, r3, xb, S, 1024, 1024);

        // 6. h2 = LN2(r3) -> r0
        ln_kernel<bf16, bf16><<<S, 256, 0, stream>>>(r3, ln2g, ln2b, r0);

        // 7. W1T -> obB[0:2M), W2T -> obB[2M:4M)
        tconv_kernel<<<dim3(64, 32, 1), 256, 0, stream>>>(W1, obB,          1024, 2048);
        tconv_kernel<<<dim3(64, 32, 1), 256, 0, stream>>>(W2, obB + 2 * M1, 1024, 2048);

        // 8. u = h2 @ W1 -> r1 (spans r1..r2, [2048][2048] bf16)
        mfma_gemm<0><<<dim3(16, 16, 1), 256, 0, stream>>>(r0, obB, r1, nullptr, S, 2048, 1024);

        // 9. sb = silu(u) * (h2 @ W2) -> r1 in-place
        mfma_gemm<3><<<dim3(16, 16, 1), 256, 0, stream>>>(r0, obB + 2 * M1, r1, nullptr, S, 2048, 1024);

        // 10. W3T -> r0 (h2 dead)
        tconv_kernel<<<dim3(32, 64, 1), 256, 0, stream>>>(W3, r0, 2048, 1024);

        // 11. out = x2 + sb @ W3 -> ob (fp32)
        mfma_gemm<4><<<dim3(8, 16, 1), 256, 0, stream>>>(r1, r0, ob, r3, S, 1024, 2048);
    }
}

// Round 6
// 629.974 us; speedup vs baseline: 4.6934x; 1.5911x over previous
//
#include <hip/hip_runtime.h>
#include <hip/hip_bf16.h>

using bf16 = __hip_bfloat16;
typedef __attribute__((ext_vector_type(8))) short bf16x8;
typedef __attribute__((ext_vector_type(4))) float f32x4;

// Shapes fixed: B=2, S=2048, D=1024, H=16, hd=64, F=2048.
// Global I/O fp32. Batches sequential. ws = 16 MB = 4 bf16 regions r0..r3
// (2M elems each). d_out half (8 MB) doubles as scratch (obB as bf16).
//
// Per-batch lifetimes (stream-ordered, audited):
//  1  LN1(xb)            -> r3
//  2  WqT/WkT/WvT        -> obB[0:1M)/[1M:2M)/[2M:3M)
//  3  QKV mfma (z=0,1,2) -> r0,r1,r2   (A=r3, B=obB+z*1M, rope z<2)
//  4  vtrans: r2 (V)     -> obB[0:2M)  (V^T [16][64][2048]; WqT/WkT dead)
//  5  attn(r0,r1,Vt=obB) -> r2         (V natural dead)
//  6  WoT -> obB[2M:3M) (WvT dead); mode2: A=r2, B=WoT, res=xb -> x2=r3
//  7  LN2(r3)            -> r0 (h2; q dead)
//  8  W1T -> obB[0:2M) (Vt dead), W2T -> obB[2M:4M) (WoT dead)
//  9  mode0: A=r0, B=W1T -> u = r1 (spans r1..r2, [2048][2048])
// 10  mode3: A=r0, B=W2T, C=r1 in-place -> sb = silu(u)*g
// 11  W3T -> r0 (h2 dead)
// 12  mode4: A=r1, B=r0(W3T), res=r3(x2) -> ob fp32 (final)

__device__ inline float toF(float x) { return x; }
__device__ inline float toF(bf16 x) { return __bfloat162float(x); }
__device__ inline void  stV(float* p, float v) { *p = v; }
__device__ inline void  stV(bf16* p, float v) { *p = __float2bfloat16(v); }

__device__ __forceinline__ void unpack8(uint4 u, float* f) {
    f[0] = __uint_as_float(u.x << 16); f[1] = __uint_as_float(u.x & 0xffff0000u);
    f[2] = __uint_as_float(u.y << 16); f[3] = __uint_as_float(u.y & 0xffff0000u);
    f[4] = __uint_as_float(u.z << 16); f[5] = __uint_as_float(u.z & 0xffff0000u);
    f[6] = __uint_as_float(u.w << 16); f[7] = __uint_as_float(u.w & 0xffff0000u);
}

__device__ __forceinline__ uint4 packbf8(const float* f) {
    union { unsigned short u[8]; uint4 v; } r;
#pragma unroll
    for (int i = 0; i < 8; i++) {
        bf16 b = __float2bfloat16(f[i]);
        r.u[i] = *(unsigned short*)&b;
    }
    return r.v;
}

__device__ __forceinline__ void gl_lds16(const void* g, void* l) {
    __builtin_amdgcn_global_load_lds(
        (__attribute__((address_space(1))) void*)g,
        (__attribute__((address_space(3))) void*)l, 16, 0, 0);
}

// ---------------------------------------------------------------------------
// LayerNorm: one block per row, D=1024, 256 threads.
// ---------------------------------------------------------------------------
template <typename Tx, typename To>
__global__ __launch_bounds__(256) void ln_kernel(
    const Tx* __restrict__ x, const float* __restrict__ g,
    const float* __restrict__ b, To* __restrict__ out)
{
    const int D = 1024;
    int row = blockIdx.x;
    int tid = threadIdx.x;
    const Tx* xr = x + (size_t)row * D;

    float vals[4];
    float sum = 0.f, sumsq = 0.f;
#pragma unroll
    for (int i = 0; i < 4; i++) {
        float v = toF(xr[tid + i * 256]);
        vals[i] = v; sum += v; sumsq += v * v;
    }
#pragma unroll
    for (int off = 32; off > 0; off >>= 1) {
        sum += __shfl_xor(sum, off);
        sumsq += __shfl_xor(sumsq, off);
    }
    __shared__ float s1[4], s2[4];
    int wave = tid >> 6, lane = tid & 63;
    if (lane == 0) { s1[wave] = sum; s2[wave] = sumsq; }
    __syncthreads();
    sum = s1[0] + s1[1] + s1[2] + s1[3];
    sumsq = s2[0] + s2[1] + s2[2] + s2[3];

    float mu = sum * (1.f / D);
    float var = sumsq * (1.f / D) - mu * mu;
    float rstd = rsqrtf(var + 1e-5f);

    To* orow = out + (size_t)row * D;
#pragma unroll
    for (int i = 0; i < 4; i++) {
        int c = tid + i * 256;
        stV(&orow[c], (vals[i] - mu) * rstd * g[c] + b[c]);
    }
}

// ---------------------------------------------------------------------------
// Transpose+convert: in fp32 [R][C] (per z-slice) -> out bf16 [C][R].
// ---------------------------------------------------------------------------
__global__ __launch_bounds__(256) void tconv_kernel(
    const float* __restrict__ in, bf16* __restrict__ out, int R, int C)
{
    __shared__ float t[32][33];
    int hh = blockIdx.z;
    const float* ip = in + (size_t)hh * R * C;
    bf16* op = out + (size_t)hh * R * C;
    int c0 = blockIdx.x * 32, r0 = blockIdx.y * 32;
    int tx = threadIdx.x & 31, ty = threadIdx.x >> 5;  // ty 0..7
#pragma unroll
    for (int i = 0; i < 4; i++)
        t[ty + 8 * i][tx] = ip[(size_t)(r0 + ty + 8 * i) * C + c0 + tx];
    __syncthreads();
#pragma unroll
    for (int i = 0; i < 4; i++)
        op[(size_t)(c0 + ty + 8 * i) * R + r0 + tx] = __float2bfloat16(t[tx][ty + 8 * i]);
}

// ---------------------------------------------------------------------------
// V transpose (bf16): v [16][2048][64] -> vt [16][64][2048]. 64x64 tiles.
// ---------------------------------------------------------------------------
__global__ __launch_bounds__(256) void vtrans_kernel(
    const bf16* __restrict__ v, bf16* __restrict__ vt)
{
    __shared__ unsigned short t[64][68];
    int hh = blockIdx.y;
    int s0 = blockIdx.x * 64;
    int tid = threadIdx.x;
    int r = tid >> 2, g = (tid & 3) * 16;

    const uint4* src = (const uint4*)(v + ((size_t)hh * 2048 + s0 + r) * 64 + g);
    *(uint4*)&t[r][g] = src[0];
    *(uint4*)&t[r][g + 8] = src[1];
    __syncthreads();

    // write vt row d=r, cols s0+g .. +16  (gather column r of tile)
    float dummy;
    (void)dummy;
    union { unsigned short u[16]; uint4 v4[2]; } o;
#pragma unroll
    for (int i = 0; i < 16; i++) o.u[i] = t[g + i][r];
    uint4* dst = (uint4*)(vt + ((size_t)hh * 64 + r) * 2048 + s0 + g);
    dst[0] = o.v4[0];
    dst[1] = o.v4[1];
}

// ---------------------------------------------------------------------------
// MFMA GEMM: C[M,N] = A[M,K](bf16) @ B (BT[N,K] bf16), fp32 accum.
// 128x128 tile, BK=32, 4 waves (2x2), 4x4 16x16 MFMA subtiles per wave.
// MODE 0: C bf16 = acc
// MODE 1: QKV scatter [H][S][64] + RoPE (z selects B/C; rope for z<2)
// MODE 2: C bf16 = acc + resF32
// MODE 3: C bf16 = silu(C) * acc   (in-place, same idx)
// MODE 4: C f32  = acc + resBf16
// ---------------------------------------------------------------------------
template <int MODE>
__global__ __launch_bounds__(256) void mfma_gemm(
    const bf16* __restrict__ A, const bf16* __restrict__ BT0,
    void* __restrict__ Cv, const void* __restrict__ resv,
    int M, int N, int K)
{
    __shared__ bf16 As[128 * 32];
    __shared__ bf16 Bs[128 * 32];
    int tid = threadIdx.x, lane = tid & 63, w = tid >> 6;
    int wm = w >> 1, wn = w & 1;
    int m0 = blockIdx.y * 128, n0 = blockIdx.x * 128;

    const bf16* BT = BT0;
    bf16* Cq = nullptr; int rope = 0;
    if (MODE == 1) {
        int z = blockIdx.z;
        BT = BT0 + ((size_t)z << 20);
        Cq = (bf16*)Cv + ((size_t)z << 21);
        rope = (z < 2);
    }

    int srow = lane >> 2, scol = (lane & 3) * 8;
    const bf16* Ag = A + (size_t)(m0 + w * 32 + srow) * K + scol;
    const bf16* Bg = BT + (size_t)(n0 + w * 32 + srow) * K + scol;
    unsigned offAB = (unsigned)__builtin_amdgcn_readfirstlane(w * 2048);
    char* As_c = (char*)As;
    char* Bs_c = (char*)Bs;

    f32x4 acc[4][4];
#pragma unroll
    for (int i = 0; i < 4; i++)
#pragma unroll
        for (int j = 0; j < 4; j++) acc[i][j] = (f32x4){0.f, 0.f, 0.f, 0.f};

    for (int k0 = 0; k0 < K; k0 += 32) {
        gl_lds16(Ag + k0,                  As_c + offAB);
        gl_lds16(Ag + k0 + (size_t)16 * K, As_c + offAB + 1024);
        gl_lds16(Bg + k0,                  Bs_c + offAB);
        gl_lds16(Bg + k0 + (size_t)16 * K, Bs_c + offAB + 1024);
        __syncthreads();

        bf16x8 af[4], bfr[4];
#pragma unroll
        for (int i = 0; i < 4; i++)
            af[i] = *(const bf16x8*)&As[(wm * 64 + i * 16 + (lane & 15)) * 32 + (lane >> 4) * 8];
#pragma unroll
        for (int j = 0; j < 4; j++)
            bfr[j] = *(const bf16x8*)&Bs[(wn * 64 + j * 16 + (lane & 15)) * 32 + (lane >> 4) * 8];
#pragma unroll
        for (int i = 0; i < 4; i++)
#pragma unroll
            for (int j = 0; j < 4; j++)
                acc[i][j] = __builtin_amdgcn_mfma_f32_16x16x32_bf16(af[i], bfr[j], acc[i][j], 0, 0, 0);
        __syncthreads();
    }

    int rbase = (lane >> 4) * 4;
    int cidx = lane & 15;
#pragma unroll
    for (int i = 0; i < 4; i++) {
#pragma unroll
        for (int j = 0; j < 4; j++) {
#pragma unroll
            for (int r = 0; r < 4; r++) {
                int row = m0 + wm * 64 + i * 16 + rbase + r;
                int col = n0 + wn * 64 + j * 16 + cidx;
                float v = acc[i][j][r];
                size_t idx = (size_t)row * N + col;
                if (MODE == 0) {
                    ((bf16*)Cv)[idx] = __float2bfloat16(v);
                } else if (MODE == 1) {
                    int h = col >> 6, kk = col & 63;
                    float outv = v;
                    if (rope) {
                        float other = __shfl_xor(v, 1);
                        float p = (float)(kk >> 1);
                        float theta = __expf(p * -0.5756462732485114f); // ln(1e4)/16
                        float ang = (float)row * theta;
                        float c, sn; __sincosf(ang, &sn, &c);
                        outv = (kk & 1) ? (v * c + other * sn) : (v * c - other * sn);
                    }
                    Cq[((size_t)h * 2048 + row) * 64 + kk] = __float2bfloat16(outv);
                } else if (MODE == 2) {
                    v += ((const float*)resv)[idx];
                    ((bf16*)Cv)[idx] = __float2bfloat16(v);
                } else if (MODE == 3) {
                    float u = __bfloat162float(((bf16*)Cv)[idx]);
                    float sg = 1.f / (1.f + __expf(-u));
                    ((bf16*)Cv)[idx] = __float2bfloat16(u * sg * v);
                } else {
                    v += __bfloat162float(((const bf16*)resv)[idx]);
                    ((float*)Cv)[idx] = v;
                }
            }
        }
    }
}

// ---------------------------------------------------------------------------
// MFMA causal flash attention (single batch). hd=64.
// q,k: [16][2048][64] bf16 (RoPE'd); vt: [16][64][2048] bf16 (V^T).
// Output o: [2048][1024] bf16 (concat heads).
// Block = 256 thr (4 waves) per 64-query tile; wave w owns rows w*16..+16.
// QK^T: A=Q (frags hoisted), B-frag reads K natural [s][d].
// PV:   P (C-layout) -> wave-private LDS bf16 -> A-frags; B-frag reads V^T.
// ---------------------------------------------------------------------------
__global__ __launch_bounds__(256) void attn_kernel(
    const bf16* __restrict__ q, const bf16* __restrict__ k,
    const bf16* __restrict__ vt, bf16* __restrict__ o)
{
    const int S = 2048;
    __shared__ bf16 Ks[64][72];
    __shared__ bf16 Vs[64][72];                     // V^T tile: [d][s]
    __shared__ __align__(16) char QPbuf[64 * 72 * 2];  // Qs [64][72] then Ps [4][16][72]
    bf16 (*Qs)[72] = (bf16 (*)[72])QPbuf;
    bf16 (*Ps)[16][72] = (bf16 (*)[16][72])QPbuf;

    int qt = 31 - (int)blockIdx.x;                  // heavy blocks first
    int h = blockIdx.y;
    int tid = threadIdx.x, lane = tid & 63, w = tid >> 6;
    int quad = lane >> 4, cidx = lane & 15;
    int m0 = qt * 64;

    const bf16* qb = q + ((size_t)h * S + m0) * 64;
    const bf16* kb = k + (size_t)h * S * 64;
    const bf16* vtb = vt + (size_t)h * 64 * S;

    int srow = tid >> 2;                            // 0..63 staging row
    int sg = (tid & 3) * 16;                        // col group (bf16 elems)

    {   // stage Q (scaled by 1/8) into Qs
        const uint4* src = (const uint4*)(qb + (size_t)srow * 64 + sg);
        uint4 u0 = src[0], u1 = src[1];
        float f[16]; unpack8(u0, f); unpack8(u1, f + 8);
#pragma unroll
        for (int i = 0; i < 16; i++) f[i] *= 0.125f;
        *(uint4*)&Qs[srow][sg] = packbf8(f);
        *(uint4*)&Qs[srow][sg + 8] = packbf8(f + 8);
    }
    __syncthreads();

    // hoist Q A-frags: A[m=cidx][k=quad*8+j (+32)]
    bf16x8 aQ0 = *(const bf16x8*)&Qs[w * 16 + cidx][quad * 8];
    bf16x8 aQ1 = *(const bf16x8*)&Qs[w * 16 + cidx][32 + quad * 8];

    float m_i[4], l_i[4];
    f32x4 Oc[4];
#pragma unroll
    for (int r = 0; r < 4; r++) { m_i[r] = -INFINITY; l_i[r] = 0.f; }
#pragma unroll
    for (int j = 0; j < 4; j++) Oc[j] = (f32x4){0.f, 0.f, 0.f, 0.f};

    for (int kt = 0; kt <= qt; kt++) {
        // global loads for this tile (issue before barrier for overlap)
        const uint4* ksrc = (const uint4*)(kb + ((size_t)(kt * 64 + srow)) * 64 + sg);
        uint4 ka0 = ksrc[0], ka1 = ksrc[1];
        const uint4* vsrc = (const uint4*)(vtb + (size_t)srow * S + kt * 64 + sg);
        uint4 va0 = vsrc[0], va1 = vsrc[1];

        __syncthreads();    // prev iteration's LDS reads complete (also: Q-frag extraction on iter 0)
        *(uint4*)&Ks[srow][sg] = ka0; *(uint4*)&Ks[srow][sg + 8] = ka1;
        *(uint4*)&Vs[srow][sg] = va0; *(uint4*)&Vs[srow][sg + 8] = va1;
        __syncthreads();

        // scores: 16x64 per wave via 8 MFMA (B-frag = K natural)
        f32x4 sc[4];
#pragma unroll
        for (int j = 0; j < 4; j++) sc[j] = (f32x4){0.f, 0.f, 0.f, 0.f};
#pragma unroll
        for (int j = 0; j < 4; j++) {
            bf16x8 bk0 = *(const bf16x8*)&Ks[j * 16 + cidx][quad * 8];
            bf16x8 bk1 = *(const bf16x8*)&Ks[j * 16 + cidx][32 + quad * 8];
            sc[j] = __builtin_amdgcn_mfma_f32_16x16x32_bf16(aQ0, bk0, sc[j], 0, 0, 0);
            sc[j] = __builtin_amdgcn_mfma_f32_16x16x32_bf16(aQ1, bk1, sc[j], 0, 0, 0);
        }

        if (kt == qt) {
#pragma unroll
            for (int j = 0; j < 4; j++)
#pragma unroll
                for (int r = 0; r < 4; r++)
                    if (j * 16 + cidx > w * 16 + quad * 4 + r) sc[j][r] = -INFINITY;
        }

        // online softmax (C-layout: row = quad*4+r, cols spread over 16 lanes x 4 j)
#pragma unroll
        for (int r = 0; r < 4; r++) {
            float mx = fmaxf(fmaxf(sc[0][r], sc[1][r]), fmaxf(sc[2][r], sc[3][r]));
            mx = fmaxf(mx, __shfl_xor(mx, 1));
            mx = fmaxf(mx, __shfl_xor(mx, 2));
            mx = fmaxf(mx, __shfl_xor(mx, 4));
            mx = fmaxf(mx, __shfl_xor(mx, 8));
            float mnew = fmaxf(m_i[r], mx);
            float alpha = __expf(m_i[r] - mnew);
            float rs = 0.f;
#pragma unroll
            for (int j = 0; j < 4; j++) { sc[j][r] = __expf(sc[j][r] - mnew); rs += sc[j][r]; }
            rs += __shfl_xor(rs, 1);
            rs += __shfl_xor(rs, 2);
            rs += __shfl_xor(rs, 4);
            rs += __shfl_xor(rs, 8);
            l_i[r] = l_i[r] * alpha + rs;
            m_i[r] = mnew;
#pragma unroll
            for (int j = 0; j < 4; j++) Oc[j][r] *= alpha;
        }

        // P: C-layout -> wave-private LDS strip (bf16)
#pragma unroll
        for (int j = 0; j < 4; j++)
#pragma unroll
            for (int r = 0; r < 4; r++)
                Ps[w][quad * 4 + r][j * 16 + cidx] = __float2bfloat16(sc[j][r]);

        // PV: A-frags from P strip, B-frags from V^T tile
        bf16x8 aP0 = *(const bf16x8*)&Ps[w][cidx][quad * 8];
        bf16x8 aP1 = *(const bf16x8*)&Ps[w][cidx][32 + quad * 8];
#pragma unroll
        for (int j = 0; j < 4; j++) {
            bf16x8 bv0 = *(const bf16x8*)&Vs[j * 16 + cidx][quad * 8];
            bf16x8 bv1 = *(const bf16x8*)&Vs[j * 16 + cidx][32 + quad * 8];
            Oc[j] = __builtin_amdgcn_mfma_f32_16x16x32_bf16(aP0, bv0, Oc[j], 0, 0, 0);
            Oc[j] = __builtin_amdgcn_mfma_f32_16x16x32_bf16(aP1, bv1, Oc[j], 0, 0, 0);
        }
    }

    // epilogue: divide by l, write [s][h*64+d]
#pragma unroll
    for (int r = 0; r < 4; r++) {
        float inv = 1.f / l_i[r];
        int row = m0 + w * 16 + quad * 4 + r;
#pragma unroll
        for (int j = 0; j < 4; j++)
            o[(size_t)row * 1024 + h * 64 + j * 16 + cidx] = __float2bfloat16(Oc[j][r] * inv);
    }
}

// ---------------------------------------------------------------------------
extern "C" void kernel_launch(void* const* d_in, const int* in_sizes, int n_in,
                              void* d_out, int out_size, void* d_ws, size_t ws_size,
                              hipStream_t stream)
{
    const int S = 2048, D = 1024;

    const float* x    = (const float*)d_in[0];
    const float* ln1g = (const float*)d_in[1];
    const float* ln1b = (const float*)d_in[2];
    const float* Wq   = (const float*)d_in[3];
    const float* Wk   = (const float*)d_in[4];
    const float* Wv   = (const float*)d_in[5];
    const float* Wo   = (const float*)d_in[6];
    const float* ln2g = (const float*)d_in[7];
    const float* ln2b = (const float*)d_in[8];
    const float* W1   = (const float*)d_in[9];
    const float* W2   = (const float*)d_in[10];
    const float* W3   = (const float*)d_in[11];
    float* out = (float*)d_out;

    const size_t NR = (size_t)S * D;   // 2M elems per 4MB region
    bf16* r0 = (bf16*)d_ws;
    bf16* r1 = r0 + NR;
    bf16* r2 = r1 + NR;
    bf16* r3 = r2 + NR;
    const size_t M1 = 1u << 20;        // 1M elems

    for (int b = 0; b < 2; b++) {
        const float* xb = x + (size_t)b * S * D;
        float* ob = out + (size_t)b * S * D;   // 8 MB scratch / final out
        bf16* obB = (bf16*)ob;

        // 1. h = LN1(xb) -> r3
        ln_kernel<float, bf16><<<S, 256, 0, stream>>>(xb, ln1g, ln1b, r3);

        // 2. WqT/WkT/WvT -> obB[0:3M)
        tconv_kernel<<<dim3(2, 32, 16), 256, 0, stream>>>(Wq, obB,          1024, 64);
        tconv_kernel<<<dim3(2, 32, 16), 256, 0, stream>>>(Wk, obB + 1 * M1, 1024, 64);
        tconv_kernel<<<dim3(2, 32, 16), 256, 0, stream>>>(Wv, obB + 2 * M1, 1024, 64);

        // 3. q,k,v (+RoPE) -> r0,r1,r2
        mfma_gemm<1><<<dim3(8, 16, 3), 256, 0, stream>>>(r3, obB, r0, nullptr, S, 1024, 1024);

        // 4. V^T -> obB[0:2M)  (WqT/WkT dead)
        vtrans_kernel<<<dim3(32, 16), 256, 0, stream>>>(r2, obB);

        // 5. attn -> r2 (V natural dead)
        attn_kernel<<<dim3(32, 16), 256, 0, stream>>>(r0, r1, obB, r2);

        // 6. WoT -> obB[2M:3M) (WvT dead); x2 = xb + attn@Wo -> r3
        tconv_kernel<<<dim3(32, 32, 1), 256, 0, stream>>>(Wo, obB + 2 * M1, 1024, 1024);
        mfma_gemm<2><<<dim3(8, 16, 1), 256, 0, stream>>>(r2, obB + 2 * M1, r3, xb, S, 1024, 1024);

        // 7. h2 = LN2(r3) -> r0
        ln_kernel<bf16, bf16><<<S, 256, 0, stream>>>(r3, ln2g, ln2b, r0);

        // 8. W1T -> obB[0:2M) (Vt dead), W2T -> obB[2M:4M) (WoT dead)
        tconv_kernel<<<dim3(64, 32, 1), 256, 0, stream>>>(W1, obB,          1024, 2048);
        tconv_kernel<<<dim3(64, 32, 1), 256, 0, stream>>>(W2, obB + 2 * M1, 1024, 2048);

        // 9. u = h2 @ W1 -> r1 (spans r1..r2)
        mfma_gemm<0><<<dim3(16, 16, 1), 256, 0, stream>>>(r0, obB, r1, nullptr, S, 2048, 1024);

        // 10. sb = silu(u) * (h2 @ W2) -> r1 in-place
        mfma_gemm<3><<<dim3(16, 16, 1), 256, 0, stream>>>(r0, obB + 2 * M1, r1, nullptr, S, 2048, 1024);

        // 11. W3T -> r0 (h2 dead)
        tconv_kernel<<<dim3(32, 64, 1), 256, 0, stream>>>(W3, r0, 2048, 1024);

        // 12. out = x2 + sb @ W3 -> ob (fp32)
        mfma_gemm<4><<<dim3(8, 16, 1), 256, 0, stream>>>(r1, r0, ob, r3, S, 1024, 2048);
    }
}